// Round 1
// baseline (3026.227 us; speedup 1.0000x reference)
//
#include <hip/hip_runtime.h>
#include <math.h>

// Problem constants (fixed by reference)
#define B_    16
#define NP_   1024
#define FEAT_ 512
#define H_    1024
#define E_    262144          // B*NP*DEG
#define K1_   820             // ceil(0.8*1024)
#define K2_   656             // ceil(0.8*820)
#define K3_   525             // ceil(0.8*656)
#define M1_   (B_*NP_)        // 16384
#define M2_   (B_*K1_)        // 13120
#define M3_   (B_*K2_)        // 10496
#define M4_   (B_*K3_)        // 8400

// ---------------- edge bookkeeping ----------------

__global__ void init_edges_kernel(const int* __restrict__ ei, int* __restrict__ esrc,
                                  int* __restrict__ edst, int* __restrict__ emask) {
    int e = blockIdx.x * 256 + threadIdx.x;
    esrc[e] = ei[e];
    edst[e] = ei[E_ + e];
    emask[e] = 1;
}

__global__ void count_kernel(const int* __restrict__ edst, const int* __restrict__ emask,
                             int* __restrict__ counts) {
    int e = blockIdx.x * 256 + threadIdx.x;
    if (emask[e]) atomicAdd(&counts[edst[e]], 1);
}

__global__ __launch_bounds__(1024) void scan_kernel(const int* __restrict__ counts,
                                                    int* __restrict__ offsets,
                                                    int* __restrict__ cursor, int N) {
    __shared__ int tmp[1024];
    __shared__ int carry_s;
    int tid = threadIdx.x;
    if (tid == 0) carry_s = 0;
    __syncthreads();
    for (int base = 0; base < N; base += 1024) {
        int i = base + tid;
        int v = (i < N) ? counts[i] : 0;
        tmp[tid] = v;
        __syncthreads();
        for (int off = 1; off < 1024; off <<= 1) {
            int t = (tid >= off) ? tmp[tid - off] : 0;
            __syncthreads();
            tmp[tid] += t;
            __syncthreads();
        }
        int carry = carry_s;
        int excl = tmp[tid] - v + carry;
        if (i < N) { offsets[i] = excl; cursor[i] = excl; }
        __syncthreads();
        if (tid == 1023) carry_s = carry + tmp[1023];
        __syncthreads();
    }
}

__global__ void fill_kernel(const int* __restrict__ esrc, const int* __restrict__ edst,
                            const int* __restrict__ emask, int* __restrict__ cursor,
                            int* __restrict__ adj) {
    int e = blockIdx.x * 256 + threadIdx.x;
    if (emask[e]) {
        int pos = atomicAdd(&cursor[edst[e]], 1);
        adj[pos] = esrc[e];
    }
}

__global__ void edge_update_kernel(int* __restrict__ esrc, int* __restrict__ edst,
                                   int* __restrict__ emask, const int* __restrict__ remap) {
    int e = blockIdx.x * 256 + threadIdx.x;
    if (emask[e]) {
        int ns = remap[esrc[e]];
        int nd = remap[edst[e]];
        if (ns >= 0 && nd >= 0) { esrc[e] = ns; edst[e] = nd; }
        else { esrc[e] = 0; edst[e] = 0; emask[e] = 0; }
    } else {
        esrc[e] = 0; edst[e] = 0;
    }
}

// ---------------- aggregation (mean over in-neighbors) ----------------

__global__ __launch_bounds__(256) void aggregate_kernel(const float* __restrict__ x,
                                                        const int* __restrict__ adj,
                                                        const int* __restrict__ offsets,
                                                        const int* __restrict__ counts,
                                                        float* __restrict__ mean, int F) {
    int node = blockIdx.x;
    int start = offsets[node];
    int cnt = counts[node];
    float d = fmaxf((float)cnt, 1.0f);
    for (int f = threadIdx.x; f < F; f += 256) {
        float acc = 0.f;
        for (int j = 0; j < cnt; ++j) {
            int s = adj[start + j];
            acc += x[(size_t)s * F + f];
        }
        mean[(size_t)node * F + f] = acc / d;
    }
}

// ---------------- fused dual GEMM: C = relu(A1*W1^T + A2*W2^T + b) ----------------
// A row-major M x K; W row-major 1024 x K; C row-major M x 1024.
// 64x64 tile, BK=16, 256 threads, 4x4 micro-tile per thread.

__global__ __launch_bounds__(256) void gemm2_relu(const float* __restrict__ A1,
                                                  const float* __restrict__ W1,
                                                  const float* __restrict__ A2,
                                                  const float* __restrict__ W2,
                                                  const float* __restrict__ bias,
                                                  float* __restrict__ C, int K) {
    __shared__ float As[16][68];
    __shared__ float Bs[16][68];
    int tid = threadIdx.x;
    int m0 = blockIdx.y * 64, n0 = blockIdx.x * 64;
    int lr = tid >> 2;            // 0..63 (row within tile for loading)
    int lc = (tid & 3) * 4;       // 0,4,8,12 (k-offset for float4 load)
    int tx = tid & 15, ty = tid >> 4;
    float acc[4][4] = {};

    for (int pass = 0; pass < 2; ++pass) {
        const float* A = pass ? A2 : A1;
        const float* W = pass ? W2 : W1;
        const float* Arow = A + (size_t)(m0 + lr) * K + lc;
        const float* Wrow = W + (size_t)(n0 + lr) * K + lc;
        for (int k0 = 0; k0 < K; k0 += 16) {
            float4 av = *(const float4*)(Arow + k0);
            float4 wv = *(const float4*)(Wrow + k0);
            __syncthreads();
            As[lc + 0][lr] = av.x; As[lc + 1][lr] = av.y;
            As[lc + 2][lr] = av.z; As[lc + 3][lr] = av.w;
            Bs[lc + 0][lr] = wv.x; Bs[lc + 1][lr] = wv.y;
            Bs[lc + 2][lr] = wv.z; Bs[lc + 3][lr] = wv.w;
            __syncthreads();
#pragma unroll
            for (int k = 0; k < 16; ++k) {
                float4 a = *(const float4*)&As[k][ty * 4];
                float4 b = *(const float4*)&Bs[k][tx * 4];
                float ar[4] = {a.x, a.y, a.z, a.w};
                float br[4] = {b.x, b.y, b.z, b.w};
#pragma unroll
                for (int i = 0; i < 4; ++i)
#pragma unroll
                    for (int j = 0; j < 4; ++j)
                        acc[i][j] += ar[i] * br[j];
            }
        }
    }

#pragma unroll
    for (int i = 0; i < 4; ++i) {
        int m = m0 + ty * 4 + i;
#pragma unroll
        for (int j = 0; j < 4; ++j) {
            int n = n0 + tx * 4 + j;
            float v = acc[i][j] + bias[n];
            C[(size_t)m * 1024 + n] = v > 0.f ? v : 0.f;
        }
    }
}

// ---------------- scoring + top-k ----------------

__global__ __launch_bounds__(256) void pnorm_kernel(const float* __restrict__ p, float* __restrict__ out) {
    __shared__ float red[256];
    float a = 0.f;
    for (int i = threadIdx.x; i < 1024; i += 256) { float v = p[i]; a += v * v; }
    red[threadIdx.x] = a;
    __syncthreads();
    for (int s = 128; s > 0; s >>= 1) {
        if (threadIdx.x < s) red[threadIdx.x] += red[threadIdx.x + s];
        __syncthreads();
    }
    if (threadIdx.x == 0) out[0] = sqrtf(red[0]);
}

__global__ __launch_bounds__(256) void score_kernel(const float* __restrict__ h,
                                                    const float* __restrict__ p,
                                                    const float* __restrict__ pn,
                                                    float* __restrict__ s) {
    int node = blockIdx.x;
    __shared__ float red[256];
    const float* row = h + (size_t)node * 1024;
    float a = 0.f;
    for (int i = threadIdx.x; i < 1024; i += 256) a += row[i] * p[i];
    red[threadIdx.x] = a;
    __syncthreads();
    for (int t = 128; t > 0; t >>= 1) {
        if (threadIdx.x < t) red[threadIdx.x] += red[threadIdx.x + t];
        __syncthreads();
    }
    if (threadIdx.x == 0) s[node] = tanhf(red[0] / pn[0]);
}

// one block per graph; bitonic sort 1024 (score,idx) pairs descending
__global__ __launch_bounds__(1024) void topk_kernel(const float* __restrict__ s, int n, int k,
                                                    int* __restrict__ old_idx, float* __restrict__ vals,
                                                    int* __restrict__ remap) {
    __shared__ float sv[1024];
    __shared__ int si[1024];
    int b = blockIdx.x, tid = threadIdx.x;
    sv[tid] = (tid < n) ? s[b * n + tid] : -INFINITY;
    si[tid] = tid;
    if (tid < n) remap[b * n + tid] = -1;
    __syncthreads();
    for (int kk = 2; kk <= 1024; kk <<= 1) {
        for (int j = kk >> 1; j > 0; j >>= 1) {
            int ixj = tid ^ j;
            if (ixj > tid) {
                bool up = ((tid & kk) == 0);   // descending blocks
                float a = sv[tid], bb = sv[ixj];
                bool sw = up ? (a < bb) : (a > bb);
                if (sw) {
                    sv[tid] = bb; sv[ixj] = a;
                    int t = si[tid]; si[tid] = si[ixj]; si[ixj] = t;
                }
            }
            __syncthreads();
        }
    }
    if (tid < k) {
        int old = b * n + si[tid];
        old_idx[b * k + tid] = old;
        vals[b * k + tid] = sv[tid];
        remap[old] = b * k + tid;
    }
}

__global__ __launch_bounds__(256) void compact_kernel(const float* __restrict__ h,
                                                      const int* __restrict__ old_idx,
                                                      const float* __restrict__ vals,
                                                      float* __restrict__ xn) {
    int j = blockIdx.x;
    int o = old_idx[j];
    float v = vals[j];
    const float* src = h + (size_t)o * 1024;
    float* dst = xn + (size_t)j * 1024;
    for (int f = threadIdx.x; f < 1024; f += 256) dst[f] = src[f] * v;
}

__global__ __launch_bounds__(256) void readout_kernel(const float* __restrict__ xn, int k,
                                                      float* __restrict__ out) {
    int b = blockIdx.y;
    int f = blockIdx.x * 256 + threadIdx.x;      // f in [0,1024)
    const float* base = xn + ((size_t)b * k) * 1024 + f;
    float mx = -INFINITY, sm = 0.f;
    for (int i = 0; i < k; ++i) {
        float v = base[(size_t)i * 1024];
        mx = fmaxf(mx, v);
        sm += v;
    }
    out[b * 2048 + f] += mx;
    out[b * 2048 + 1024 + f] += sm / (float)k;
}

// ---------------- host-side layer driver ----------------

static void run_layer(const float* cur, int F, int M, int n_per, int k_keep,
                      const float* Wl, const float* bias, const float* Wr, const float* p,
                      float* bufAgg, float* bufOut, float* bufNext,
                      int* esrc, int* edst, int* emask,
                      int* counts, int* offsets, int* cursor, int* adj,
                      float* scores, int* old_idx, float* vals, int* remap, float* pnorm,
                      float* out, hipStream_t stream) {
    hipMemsetAsync(counts, 0, (size_t)M * sizeof(int), stream);
    count_kernel<<<E_ / 256, 256, 0, stream>>>(edst, emask, counts);
    scan_kernel<<<1, 1024, 0, stream>>>(counts, offsets, cursor, M);
    fill_kernel<<<E_ / 256, 256, 0, stream>>>(esrc, edst, emask, cursor, adj);
    aggregate_kernel<<<M, 256, 0, stream>>>(cur, adj, offsets, counts, bufAgg, F);
    dim3 g(16, M / 64);
    gemm2_relu<<<g, 256, 0, stream>>>(bufAgg, Wl, cur, Wr, bias, bufOut, F);
    pnorm_kernel<<<1, 256, 0, stream>>>(p, pnorm);
    score_kernel<<<M, 256, 0, stream>>>(bufOut, p, pnorm, scores);
    topk_kernel<<<B_, 1024, 0, stream>>>(scores, n_per, k_keep, old_idx, vals, remap);
    edge_update_kernel<<<E_ / 256, 256, 0, stream>>>(esrc, edst, emask, remap);
    compact_kernel<<<B_ * k_keep, 256, 0, stream>>>(bufOut, old_idx, vals, bufNext);
    readout_kernel<<<dim3(4, B_), 256, 0, stream>>>(bufNext, k_keep, out);
}

extern "C" void kernel_launch(void* const* d_in, const int* in_sizes, int n_in,
                              void* d_out, int out_size, void* d_ws, size_t ws_size,
                              hipStream_t stream) {
    const float* x   = (const float*)d_in[0];
    const int*   ei  = (const int*)d_in[1];
    const float* W1l = (const float*)d_in[3];
    const float* b1  = (const float*)d_in[4];
    const float* W1r = (const float*)d_in[5];
    const float* p1  = (const float*)d_in[6];
    const float* W2l = (const float*)d_in[7];
    const float* b2  = (const float*)d_in[8];
    const float* W2r = (const float*)d_in[9];
    const float* p2  = (const float*)d_in[10];
    const float* W3l = (const float*)d_in[11];
    const float* b3  = (const float*)d_in[12];
    const float* W3r = (const float*)d_in[13];
    const float* p3  = (const float*)d_in[14];
    float* out = (float*)d_out;

    char* ws = (char*)d_ws;
    // big feature buffers
    const size_t SZ_OUT = (size_t)M1_ * H_ * 4;   // 64 MB
    const size_t SZ_CUR = (size_t)M2_ * H_ * 4;   // ~51.3 MB
    float* bufOut = (float*)(ws);
    float* bufCur = (float*)(ws + SZ_OUT);
    float* bufAgg = (float*)(ws + SZ_OUT + SZ_CUR);
    char* misc = ws + SZ_OUT + 2 * SZ_CUR;        // agg max size == SZ_CUR
    float* scores = (float*)(misc + 0 * 65536);
    int*   counts = (int*)(misc + 1 * 65536);
    int*   offsets= (int*)(misc + 2 * 65536);
    int*   cursor = (int*)(misc + 3 * 65536);
    int*   old_idx= (int*)(misc + 4 * 65536);
    float* vals   = (float*)(misc + 5 * 65536);
    int*   remap  = (int*)(misc + 6 * 65536);
    float* pnorm  = (float*)(misc + 7 * 65536);
    int*   adj    = (int*)(misc + 8 * 65536);
    int*   esrc   = (int*)(misc + 8 * 65536 + 1 * 1048576);
    int*   edst   = (int*)(misc + 8 * 65536 + 2 * 1048576);
    int*   emask  = (int*)(misc + 8 * 65536 + 3 * 1048576);

    hipMemsetAsync(d_out, 0, (size_t)out_size * sizeof(float), stream);
    init_edges_kernel<<<E_ / 256, 256, 0, stream>>>(ei, esrc, edst, emask);

    // layer 1: cur = x (FEAT=512), M=16384, pool 1024->820
    run_layer(x, FEAT_, M1_, NP_, K1_, W1l, b1, W1r, p1,
              bufAgg, bufOut, bufCur, esrc, edst, emask,
              counts, offsets, cursor, adj, scores, old_idx, vals, remap, pnorm,
              out, stream);
    // layer 2: cur = pooled (H=1024), M=13120, pool 820->656
    run_layer(bufCur, H_, M2_, K1_, K2_, W2l, b2, W2r, p2,
              bufAgg, bufOut, bufCur, esrc, edst, emask,
              counts, offsets, cursor, adj, scores, old_idx, vals, remap, pnorm,
              out, stream);
    // layer 3: cur = pooled (H=1024), M=10496, pool 656->525
    run_layer(bufCur, H_, M3_, K2_, K3_, W3l, b3, W3r, p3,
              bufAgg, bufOut, bufCur, esrc, edst, emask,
              counts, offsets, cursor, adj, scores, old_idx, vals, remap, pnorm,
              out, stream);
}

// Round 2
// 1927.101 us; speedup vs baseline: 1.5704x; 1.5704x over previous
//
#include <hip/hip_runtime.h>
#include <math.h>

// Problem constants (fixed by reference)
#define B_    16
#define NP_   1024
#define FEAT_ 512
#define H_    1024
#define E_    262144          // B*NP*DEG
#define K1_   820             // ceil(0.8*1024)
#define K2_   656             // ceil(0.8*820)
#define K3_   525             // ceil(0.8*656)
#define M1_   16384           // B*NP
#define M2_   13120           // B*K1
#define M3_   10496           // B*K2
#define MP1_  16384           // padded to x128
#define MP2_  13184
#define MP3_  10496

typedef unsigned short ushort_t;
typedef __bf16 bf16x8 __attribute__((ext_vector_type(8)));
typedef float f32x4 __attribute__((ext_vector_type(4)));

// ---- bf16 split helpers (RNE) ----
__device__ inline ushort_t f2bf(float f) {
    unsigned u = __float_as_uint(f);
    u += 0x7FFF + ((u >> 16) & 1);
    return (ushort_t)(u >> 16);
}
__device__ inline float bf2f(ushort_t h) {
    return __uint_as_float(((unsigned)h) << 16);
}

__device__ inline void gll16(const void* g, void* l) {
    __builtin_amdgcn_global_load_lds((__attribute__((address_space(1))) void*)g,
                                     (__attribute__((address_space(3))) void*)l, 16, 0, 0);
}

// ---------------- edge bookkeeping ----------------

__global__ void init_edges_kernel(const int* __restrict__ ei, int* __restrict__ esrc,
                                  int* __restrict__ edst, int* __restrict__ emask) {
    int e = blockIdx.x * 256 + threadIdx.x;
    esrc[e] = ei[e];
    edst[e] = ei[E_ + e];
    emask[e] = 1;
}

__global__ void count_kernel(const int* __restrict__ edst, const int* __restrict__ emask,
                             int* __restrict__ counts) {
    int e = blockIdx.x * 256 + threadIdx.x;
    if (emask[e]) atomicAdd(&counts[edst[e]], 1);
}

__global__ __launch_bounds__(1024) void scan_kernel(const int* __restrict__ counts,
                                                    int* __restrict__ offsets,
                                                    int* __restrict__ cursor, int N) {
    __shared__ int tmp[1024];
    __shared__ int carry_s;
    int tid = threadIdx.x;
    if (tid == 0) carry_s = 0;
    __syncthreads();
    for (int base = 0; base < N; base += 1024) {
        int i = base + tid;
        int v = (i < N) ? counts[i] : 0;
        tmp[tid] = v;
        __syncthreads();
        for (int off = 1; off < 1024; off <<= 1) {
            int t = (tid >= off) ? tmp[tid - off] : 0;
            __syncthreads();
            tmp[tid] += t;
            __syncthreads();
        }
        int carry = carry_s;
        int excl = tmp[tid] - v + carry;
        if (i < N) { offsets[i] = excl; cursor[i] = excl; }
        __syncthreads();
        if (tid == 1023) carry_s = carry + tmp[1023];
        __syncthreads();
    }
}

__global__ void fill_kernel(const int* __restrict__ esrc, const int* __restrict__ edst,
                            const int* __restrict__ emask, int* __restrict__ cursor,
                            int* __restrict__ adj) {
    int e = blockIdx.x * 256 + threadIdx.x;
    if (emask[e]) {
        int pos = atomicAdd(&cursor[edst[e]], 1);
        adj[pos] = esrc[e];
    }
}

__global__ void edge_update_kernel(int* __restrict__ esrc, int* __restrict__ edst,
                                   int* __restrict__ emask, const int* __restrict__ remap) {
    int e = blockIdx.x * 256 + threadIdx.x;
    if (emask[e]) {
        int ns = remap[esrc[e]];
        int nd = remap[edst[e]];
        if (ns >= 0 && nd >= 0) { esrc[e] = ns; edst[e] = nd; }
        else { esrc[e] = 0; edst[e] = 0; emask[e] = 0; }
    } else {
        esrc[e] = 0; edst[e] = 0;
    }
}

// ---------------- packing kernels (fp32 -> split bf16 hi/lo) ----------------
// Abig row layout (4K cols, bf16): [agg_hi(K) | agg_lo(K) | cur_hi(K) | cur_lo(K)]
// Wbig row layout (4K cols, bf16): [Wl_hi(K)  | Wl_lo(K)  | Wr_hi(K)  | Wr_lo(K)]

// mean aggregation, packed directly into Abig cols [0, 2K)
__global__ __launch_bounds__(256) void aggregate_pack_kernel(const float* __restrict__ x,
                                                             const int* __restrict__ adj,
                                                             const int* __restrict__ offsets,
                                                             const int* __restrict__ counts,
                                                             ushort_t* __restrict__ Abig,
                                                             int K, int M) {
    int node = blockIdx.x;
    ushort_t* row = Abig + (size_t)node * (4 * K);
    if (node >= M) {
        for (int f = threadIdx.x; f < 2 * K; f += 256) row[f] = 0;
        return;
    }
    int start = offsets[node];
    int cnt = counts[node];
    float d = fmaxf((float)cnt, 1.0f);
    for (int f = threadIdx.x; f < K; f += 256) {
        float acc = 0.f;
        for (int j = 0; j < cnt; ++j) {
            int s = adj[start + j];
            acc += x[(size_t)s * K + f];
        }
        float mean = acc / d;
        ushort_t h = f2bf(mean);
        ushort_t l = f2bf(mean - bf2f(h));
        row[f] = h;
        row[K + f] = l;
    }
}

// pack node features into Abig cols [2K, 4K)
__global__ __launch_bounds__(256) void pack_cur_kernel(const float* __restrict__ cur,
                                                       ushort_t* __restrict__ Abig,
                                                       int K, int M) {
    int m = blockIdx.y;
    int k = blockIdx.x * 256 + threadIdx.x;
    float v = (m < M) ? cur[(size_t)m * K + k] : 0.f;
    ushort_t h = f2bf(v);
    ushort_t l = f2bf(v - bf2f(h));
    ushort_t* row = Abig + (size_t)m * (4 * K) + 2 * K;
    row[k] = h;
    row[K + k] = l;
}

__global__ __launch_bounds__(256) void pack_w_kernel(const float* __restrict__ Wl,
                                                     const float* __restrict__ Wr,
                                                     ushort_t* __restrict__ Wbig, int K) {
    int idx = blockIdx.x * 256 + threadIdx.x;    // over 1024*K
    int n = idx / K;
    int k = idx - n * K;
    ushort_t* row = Wbig + (size_t)n * (4 * K);
    float a = Wl[idx];
    ushort_t ah = f2bf(a);
    row[k] = ah;
    row[K + k] = f2bf(a - bf2f(ah));
    float b = Wr[idx];
    ushort_t bh = f2bf(b);
    row[2 * K + k] = bh;
    row[3 * K + k] = f2bf(b - bf2f(bh));
}

// ---------------- MFMA GEMM: C = relu(sum of 6 diagonal K-segments + bias) ----------------
// Segments: (Ah,Wh)(Al,Wh)(Ah,Wl) for agg*Wl, same trio for cur*Wr -> split-bf16 fp32-accurate.
// 128x128 tile, BK=32, 256 threads (4 waves, each 64x64 = 4x4 frags of 16x16x32).

__global__ __launch_bounds__(256) void gemm_mfma(const ushort_t* __restrict__ Ab,
                                                 const ushort_t* __restrict__ Wb,
                                                 const float* __restrict__ bias,
                                                 float* __restrict__ C, int K) {
    __shared__ ushort_t lA[128 * 32];
    __shared__ ushort_t lB[128 * 32];
    const int LD = 4 * K;
    int tid = threadIdx.x;
    int lane = tid & 63;
    int w = tid >> 6;
    int wr = (w >> 1) * 64, wc = (w & 1) * 64;
    int m0 = blockIdx.y * 128, n0 = blockIdx.x * 128;

    int srow = tid >> 2;                 // 0..63
    int schunk = (tid & 3) * 8;          // element offset (8 bf16 = 16 B)
    const ushort_t* Ag = Ab + (size_t)(m0 + srow) * LD + schunk;
    const ushort_t* Bg = Wb + (size_t)(n0 + srow) * LD + schunk;
    ushort_t* lAp = &lA[srow * 32 + schunk];
    ushort_t* lBp = &lB[srow * 32 + schunk];
    const size_t rstep = (size_t)64 * LD;

    f32x4 acc[4][4];
#pragma unroll
    for (int i = 0; i < 4; ++i)
#pragma unroll
        for (int j = 0; j < 4; ++j) acc[i][j] = (f32x4){0.f, 0.f, 0.f, 0.f};

    const int aoffs[6] = {0, K, 0, 2 * K, 3 * K, 2 * K};
    const int woffs[6] = {0, 0, K, 2 * K, 2 * K, 3 * K};

    int aidx = (wr + (lane & 15)) * 32 + (lane >> 4) * 8;
    int bidx = (wc + (lane & 15)) * 32 + (lane >> 4) * 8;

    for (int seg = 0; seg < 6; ++seg) {
        const ushort_t* As = Ag + aoffs[seg];
        const ushort_t* Bs = Bg + woffs[seg];
        for (int kk = 0; kk < K; kk += 32) {
            __syncthreads();
            gll16(As + kk, lAp);
            gll16(As + kk + rstep, lAp + 64 * 32);
            gll16(Bs + kk, lBp);
            gll16(Bs + kk + rstep, lBp + 64 * 32);
            __syncthreads();
            bf16x8 af[4], bfr[4];
#pragma unroll
            for (int i = 0; i < 4; ++i)
                af[i] = *(const bf16x8*)&lA[aidx + i * 16 * 32];
#pragma unroll
            for (int j = 0; j < 4; ++j)
                bfr[j] = *(const bf16x8*)&lB[bidx + j * 16 * 32];
#pragma unroll
            for (int i = 0; i < 4; ++i)
#pragma unroll
                for (int j = 0; j < 4; ++j)
                    acc[i][j] = __builtin_amdgcn_mfma_f32_16x16x32_bf16(af[i], bfr[j], acc[i][j], 0, 0, 0);
        }
    }

    float bj[4];
#pragma unroll
    for (int j = 0; j < 4; ++j) bj[j] = bias[n0 + wc + j * 16 + (lane & 15)];
#pragma unroll
    for (int i = 0; i < 4; ++i) {
        int row0 = m0 + wr + i * 16 + (lane >> 4) * 4;
#pragma unroll
        for (int j = 0; j < 4; ++j) {
            int col = n0 + wc + j * 16 + (lane & 15);
#pragma unroll
            for (int r = 0; r < 4; ++r) {
                float v = acc[i][j][r] + bj[j];
                C[(size_t)(row0 + r) * 1024 + col] = v > 0.f ? v : 0.f;
            }
        }
    }
}

// ---------------- scoring + top-k ----------------

__global__ __launch_bounds__(256) void pnorm_kernel(const float* __restrict__ p, float* __restrict__ out) {
    __shared__ float red[256];
    float a = 0.f;
    for (int i = threadIdx.x; i < 1024; i += 256) { float v = p[i]; a += v * v; }
    red[threadIdx.x] = a;
    __syncthreads();
    for (int s = 128; s > 0; s >>= 1) {
        if (threadIdx.x < s) red[threadIdx.x] += red[threadIdx.x + s];
        __syncthreads();
    }
    if (threadIdx.x == 0) out[0] = sqrtf(red[0]);
}

__global__ __launch_bounds__(256) void score_kernel(const float* __restrict__ h,
                                                    const float* __restrict__ p,
                                                    const float* __restrict__ pn,
                                                    float* __restrict__ s) {
    int node = blockIdx.x;
    __shared__ float red[256];
    const float* row = h + (size_t)node * 1024;
    float a = 0.f;
    for (int i = threadIdx.x; i < 1024; i += 256) a += row[i] * p[i];
    red[threadIdx.x] = a;
    __syncthreads();
    for (int t = 128; t > 0; t >>= 1) {
        if (threadIdx.x < t) red[threadIdx.x] += red[threadIdx.x + t];
        __syncthreads();
    }
    if (threadIdx.x == 0) s[node] = tanhf(red[0] / pn[0]);
}

// one block per graph; bitonic sort 1024 (score,idx) pairs descending
__global__ __launch_bounds__(1024) void topk_kernel(const float* __restrict__ s, int n, int k,
                                                    int* __restrict__ old_idx, float* __restrict__ vals,
                                                    int* __restrict__ remap) {
    __shared__ float sv[1024];
    __shared__ int si[1024];
    int b = blockIdx.x, tid = threadIdx.x;
    sv[tid] = (tid < n) ? s[b * n + tid] : -INFINITY;
    si[tid] = tid;
    if (tid < n) remap[b * n + tid] = -1;
    __syncthreads();
    for (int kk = 2; kk <= 1024; kk <<= 1) {
        for (int j = kk >> 1; j > 0; j >>= 1) {
            int ixj = tid ^ j;
            if (ixj > tid) {
                bool up = ((tid & kk) == 0);
                float a = sv[tid], bb = sv[ixj];
                bool sw = up ? (a < bb) : (a > bb);
                if (sw) {
                    sv[tid] = bb; sv[ixj] = a;
                    int t = si[tid]; si[tid] = si[ixj]; si[ixj] = t;
                }
            }
            __syncthreads();
        }
    }
    if (tid < k) {
        int old = b * n + si[tid];
        old_idx[b * k + tid] = old;
        vals[b * k + tid] = sv[tid];
        remap[old] = b * k + tid;
    }
}

__global__ __launch_bounds__(256) void compact_kernel(const float* __restrict__ h,
                                                      const int* __restrict__ old_idx,
                                                      const float* __restrict__ vals,
                                                      float* __restrict__ xn) {
    int j = blockIdx.x;
    int o = old_idx[j];
    float v = vals[j];
    const float* src = h + (size_t)o * 1024;
    float* dst = xn + (size_t)j * 1024;
    for (int f = threadIdx.x; f < 1024; f += 256) dst[f] = src[f] * v;
}

__global__ __launch_bounds__(256) void readout_kernel(const float* __restrict__ xn, int k,
                                                      float* __restrict__ out) {
    int b = blockIdx.y;
    int f = blockIdx.x * 256 + threadIdx.x;
    const float* base = xn + ((size_t)b * k) * 1024 + f;
    float mx = -INFINITY, sm = 0.f;
    for (int i = 0; i < k; ++i) {
        float v = base[(size_t)i * 1024];
        mx = fmaxf(mx, v);
        sm += v;
    }
    out[b * 2048 + f] += mx;
    out[b * 2048 + 1024 + f] += sm / (float)k;
}

// ---------------- host-side layer driver ----------------

static void run_layer(const float* cur, int K, int M, int Mp, int n_per, int k_keep,
                      const float* Wl, const float* bias, const float* Wr, const float* p,
                      ushort_t* Abig, ushort_t* Wbig, float* bufOut, float* bufNext,
                      int* esrc, int* edst, int* emask,
                      int* counts, int* offsets, int* cursor, int* adj,
                      float* scores, int* old_idx, float* vals, int* remap, float* pnormv,
                      float* out, hipStream_t stream) {
    hipMemsetAsync(counts, 0, (size_t)M * sizeof(int), stream);
    count_kernel<<<E_ / 256, 256, 0, stream>>>(edst, emask, counts);
    scan_kernel<<<1, 1024, 0, stream>>>(counts, offsets, cursor, M);
    fill_kernel<<<E_ / 256, 256, 0, stream>>>(esrc, edst, emask, cursor, adj);
    aggregate_pack_kernel<<<Mp, 256, 0, stream>>>(cur, adj, offsets, counts, Abig, K, M);
    pack_cur_kernel<<<dim3(K / 256, Mp), 256, 0, stream>>>(cur, Abig, K, M);
    pack_w_kernel<<<(1024 * K) / 256, 256, 0, stream>>>(Wl, Wr, Wbig, K);
    gemm_mfma<<<dim3(8, Mp / 128), 256, 0, stream>>>(Abig, Wbig, bias, bufOut, K);
    pnorm_kernel<<<1, 256, 0, stream>>>(p, pnormv);
    score_kernel<<<M, 256, 0, stream>>>(bufOut, p, pnormv, scores);
    topk_kernel<<<B_, 1024, 0, stream>>>(scores, n_per, k_keep, old_idx, vals, remap);
    edge_update_kernel<<<E_ / 256, 256, 0, stream>>>(esrc, edst, emask, remap);
    compact_kernel<<<B_ * k_keep, 256, 0, stream>>>(bufOut, old_idx, vals, bufNext);
    readout_kernel<<<dim3(4, B_), 256, 0, stream>>>(bufNext, k_keep, out);
}

extern "C" void kernel_launch(void* const* d_in, const int* in_sizes, int n_in,
                              void* d_out, int out_size, void* d_ws, size_t ws_size,
                              hipStream_t stream) {
    const float* x   = (const float*)d_in[0];
    const int*   ei  = (const int*)d_in[1];
    const float* W1l = (const float*)d_in[3];
    const float* b1  = (const float*)d_in[4];
    const float* W1r = (const float*)d_in[5];
    const float* p1  = (const float*)d_in[6];
    const float* W2l = (const float*)d_in[7];
    const float* b2  = (const float*)d_in[8];
    const float* W2r = (const float*)d_in[9];
    const float* p2  = (const float*)d_in[10];
    const float* W3l = (const float*)d_in[11];
    const float* b3  = (const float*)d_in[12];
    const float* W3r = (const float*)d_in[13];
    const float* p3  = (const float*)d_in[14];
    float* out = (float*)d_out;

    char* ws = (char*)d_ws;
    size_t off = 0;
    float* bufOut = (float*)(ws + off); off += (size_t)MP1_ * 1024 * 4;            // 64 MB
    float* bufCur = (float*)(ws + off); off += (size_t)M2_ * 1024 * 4;             // 51.3 MB
    ushort_t* Abig = (ushort_t*)(ws + off); off += (size_t)MP2_ * 4096 * 2;        // 103 MB
    ushort_t* Wbig = (ushort_t*)(ws + off); off += (size_t)1024 * 4096 * 2;        // 8 MB
    char* misc = ws + off;
    float* scores = (float*)(misc + 0 * 65536);
    int*   counts = (int*)(misc + 1 * 65536);
    int*   offsets= (int*)(misc + 2 * 65536);
    int*   cursor = (int*)(misc + 3 * 65536);
    int*   old_idx= (int*)(misc + 4 * 65536);
    float* vals   = (float*)(misc + 5 * 65536);
    int*   remap  = (int*)(misc + 6 * 65536);
    float* pnormv = (float*)(misc + 7 * 65536);
    int*   adj    = (int*)(misc + 8 * 65536);
    int*   esrc   = (int*)(misc + 8 * 65536 + 1 * 1048576);
    int*   edst   = (int*)(misc + 8 * 65536 + 2 * 1048576);
    int*   emask  = (int*)(misc + 8 * 65536 + 3 * 1048576);

    hipMemsetAsync(d_out, 0, (size_t)out_size * sizeof(float), stream);
    init_edges_kernel<<<E_ / 256, 256, 0, stream>>>(ei, esrc, edst, emask);

    // layer 1: cur = x (K=512), M=16384, pool 1024->820
    run_layer(x, FEAT_, M1_, MP1_, NP_, K1_, W1l, b1, W1r, p1,
              Abig, Wbig, bufOut, bufCur, esrc, edst, emask,
              counts, offsets, cursor, adj, scores, old_idx, vals, remap, pnormv,
              out, stream);
    // layer 2: cur = pooled (K=1024), M=13120, pool 820->656
    run_layer(bufCur, H_, M2_, MP2_, K1_, K2_, W2l, b2, W2r, p2,
              Abig, Wbig, bufOut, bufCur, esrc, edst, emask,
              counts, offsets, cursor, adj, scores, old_idx, vals, remap, pnormv,
              out, stream);
    // layer 3: cur = pooled (K=1024), M=10496, pool 656->525
    run_layer(bufCur, H_, M3_, MP3_, K2_, K3_, W3l, b3, W3r, p3,
              Abig, Wbig, bufOut, bufCur, esrc, edst, emask,
              counts, offsets, cursor, adj, scores, old_idx, vals, remap, pnormv,
              out, stream);
}

// Round 3
// 1713.307 us; speedup vs baseline: 1.7663x; 1.1248x over previous
//
#include <hip/hip_runtime.h>
#include <math.h>

// Problem constants (fixed by reference)
#define B_    16
#define NP_   1024
#define FEAT_ 512
#define H_    1024
#define E_    262144          // B*NP*DEG
#define K1_   820             // ceil(0.8*1024)
#define K2_   656             // ceil(0.8*820)
#define K3_   525             // ceil(0.8*656)
#define M1_   16384           // B*NP
#define M2_   13120           // B*K1
#define M3_   10496           // B*K2
#define MP1_  16384           // padded to x128
#define MP2_  13184
#define MP3_  10496

typedef unsigned short ushort_t;
typedef __bf16 bf16x8 __attribute__((ext_vector_type(8)));
typedef float f32x4 __attribute__((ext_vector_type(4)));

// ---- bf16 split helpers (RNE) ----
__device__ inline ushort_t f2bf(float f) {
    unsigned u = __float_as_uint(f);
    u += 0x7FFF + ((u >> 16) & 1);
    return (ushort_t)(u >> 16);
}
__device__ inline float bf2f(ushort_t h) {
    return __uint_as_float(((unsigned)h) << 16);
}

__device__ inline void gll16(const void* g, void* l) {
    __builtin_amdgcn_global_load_lds((__attribute__((address_space(1))) void*)g,
                                     (__attribute__((address_space(3))) void*)l, 16, 0, 0);
}

// ---------------- edge bookkeeping ----------------

__global__ void init_edges_kernel(const int* __restrict__ ei, int* __restrict__ esrc,
                                  int* __restrict__ edst, int* __restrict__ emask) {
    int e = blockIdx.x * 256 + threadIdx.x;
    esrc[e] = ei[e];
    edst[e] = ei[E_ + e];
    emask[e] = 1;
}

__global__ void count_kernel(const int* __restrict__ edst, const int* __restrict__ emask,
                             int* __restrict__ counts) {
    int e = blockIdx.x * 256 + threadIdx.x;
    if (emask[e]) atomicAdd(&counts[edst[e]], 1);
}

// single-block scan: 1024 threads x 16 items serial + one block-scan of partials
__global__ __launch_bounds__(1024) void scan16_kernel(const int* __restrict__ counts,
                                                      int* __restrict__ offsets,
                                                      int* __restrict__ cursor, int M) {
    __shared__ int part[1024];
    int t = threadIdx.x;
    int base = t * 16;
    int v[16];
    int s = 0;
#pragma unroll
    for (int i = 0; i < 16; ++i) {
        int idx = base + i;
        v[i] = s;
        int c = (idx < M) ? counts[idx] : 0;
        s += c;
    }
    part[t] = s;
    __syncthreads();
    for (int off = 1; off < 1024; off <<= 1) {
        int tv = (t >= off) ? part[t - off] : 0;
        __syncthreads();
        part[t] += tv;
        __syncthreads();
    }
    int excl = part[t] - s;
#pragma unroll
    for (int i = 0; i < 16; ++i) {
        int idx = base + i;
        if (idx < M) {
            int o = excl + v[i];
            offsets[idx] = o;
            cursor[idx] = o;
        }
    }
}

__global__ void fill_kernel(const int* __restrict__ esrc, const int* __restrict__ edst,
                            const int* __restrict__ emask, int* __restrict__ cursor,
                            int* __restrict__ adj) {
    int e = blockIdx.x * 256 + threadIdx.x;
    if (emask[e]) {
        int pos = atomicAdd(&cursor[edst[e]], 1);
        adj[pos] = esrc[e];
    }
}

__global__ void edge_update_kernel(int* __restrict__ esrc, int* __restrict__ edst,
                                   int* __restrict__ emask, const int* __restrict__ remap) {
    int e = blockIdx.x * 256 + threadIdx.x;
    if (emask[e]) {
        int ns = remap[esrc[e]];
        int nd = remap[edst[e]];
        if (ns >= 0 && nd >= 0) { esrc[e] = ns; edst[e] = nd; }
        else { esrc[e] = 0; edst[e] = 0; emask[e] = 0; }
    } else {
        esrc[e] = 0; edst[e] = 0;
    }
}

// ---------------- fused aggregation + pack (fp32 -> 4 bf16 planes) ----------------
// Abig row layout (4K cols, bf16): [agg_hi(K) | agg_lo(K) | cur_hi(K) | cur_lo(K)]

__global__ __launch_bounds__(256) void agg_pack_kernel(const float* __restrict__ x,
                                                       const int* __restrict__ adj,
                                                       const int* __restrict__ offsets,
                                                       const int* __restrict__ counts,
                                                       ushort_t* __restrict__ Abig,
                                                       int K, int M) {
    int node = blockIdx.x;
    ushort_t* row = Abig + (size_t)node * (4 * K);
    if (node >= M) {
        for (int f = threadIdx.x; f < 4 * K; f += 256) row[f] = 0;
        return;
    }
    int start = offsets[node], cnt = counts[node];
    float d = fmaxf((float)cnt, 1.0f);
    int NF = K >> 8;                         // 2 (K=512) or 4 (K=1024)
    float acc[4] = {0.f, 0.f, 0.f, 0.f};
    const float* xb = x + threadIdx.x;
    for (int j = 0; j < cnt; ++j) {
        const float* sr = xb + (size_t)adj[start + j] * K;
#pragma unroll
        for (int u = 0; u < 4; ++u)
            if (u < NF) acc[u] += sr[u * 256];
    }
    const float* cr = x + (size_t)node * K + threadIdx.x;
#pragma unroll
    for (int u = 0; u < 4; ++u) {
        if (u < NF) {
            int f = threadIdx.x + u * 256;
            float mean = acc[u] / d;
            ushort_t mh = f2bf(mean);
            row[f] = mh;
            row[K + f] = f2bf(mean - bf2f(mh));
            float cv = cr[u * 256];
            ushort_t ch = f2bf(cv);
            row[2 * K + f] = ch;
            row[3 * K + f] = f2bf(cv - bf2f(ch));
        }
    }
}

__global__ __launch_bounds__(256) void pack_w_kernel(const float* __restrict__ Wl,
                                                     const float* __restrict__ Wr,
                                                     ushort_t* __restrict__ Wbig, int K) {
    int idx = blockIdx.x * 256 + threadIdx.x;    // over 1024*K
    int n = idx / K;
    int k = idx - n * K;
    ushort_t* row = Wbig + (size_t)n * (4 * K);
    float a = Wl[idx];
    ushort_t ah = f2bf(a);
    row[k] = ah;
    row[K + k] = f2bf(a - bf2f(ah));
    float b = Wr[idx];
    ushort_t bh = f2bf(b);
    row[2 * K + k] = bh;
    row[3 * K + k] = f2bf(b - bf2f(bh));
}

// ---------------- MFMA GEMM, two super-segments, XOR-swizzled LDS ----------------
// Per superseg ss: acc += Ah*Wh + Al*Wh + Ah*Wl  (planes at cols ss*2K + {0,K}).
// 128x128 tile, BK=32, 256 threads (4 waves of 64x64 = 4x4 frags of 16x16x32).
// Staging: lane fetches global quad gq = f ^ (row&3) ^ ((row>>2)&3) so that the
// dense lane-order LDS placement forced by global_load_lds yields a 2-way
// (free) bank pattern on the ds_read_b128 fragment reads.

__global__ __launch_bounds__(256) void gemm_mfma(const ushort_t* __restrict__ Ab,
                                                 const ushort_t* __restrict__ Wb,
                                                 const float* __restrict__ bias,
                                                 float* __restrict__ C, int K) {
    __shared__ ushort_t lA0[4096];   // A hi plane tile  (128 rows x 32, swizzled)
    __shared__ ushort_t lA1[4096];   // A lo plane tile
    __shared__ ushort_t lB0[4096];   // W hi plane tile
    __shared__ ushort_t lB1[4096];   // W lo plane tile
    const int LD = 4 * K;
    int tid = threadIdx.x;
    int lane = tid & 63;
    int w = tid >> 6;
    int wr = (w >> 1) * 64, wc = (w & 1) * 64;
    int m0 = blockIdx.y * 128, n0 = blockIdx.x * 128;

    // staging: unit u = c*256 + tid; row = u>>2, field f = tid&3, fetch quad gq
    int srow = tid >> 2;
    int gq = (tid & 3) ^ ((tid >> 2) & 3) ^ ((tid >> 4) & 3);
    const ushort_t* Ag = Ab + (size_t)(m0 + srow) * LD + gq * 8;
    const ushort_t* Bg = Wb + (size_t)(n0 + srow) * LD + gq * 8;
    ushort_t* lA0p = &lA0[tid * 8];
    ushort_t* lA1p = &lA1[tid * 8];
    ushort_t* lB0p = &lB0[tid * 8];
    ushort_t* lB1p = &lB1[tid * 8];
    const size_t rstep = (size_t)64 * LD;

    // fragment read swizzle: quad field = q ^ (row&3) ^ ((row>>2)&3), uniform per lane
    int qsw = (lane >> 4) ^ (lane & 3) ^ ((lane >> 2) & 3);
    int aidx = (wr + (lane & 15)) * 32 + qsw * 8;
    int bidx = (wc + (lane & 15)) * 32 + qsw * 8;

    f32x4 acc[4][4];
#pragma unroll
    for (int i = 0; i < 4; ++i)
#pragma unroll
        for (int j = 0; j < 4; ++j) acc[i][j] = (f32x4){0.f, 0.f, 0.f, 0.f};

    for (int ss = 0; ss < 2; ++ss) {
        const ushort_t* Ah = Ag + ss * 2 * K;
        const ushort_t* Bh = Bg + ss * 2 * K;
        for (int kk = 0; kk < K; kk += 32) {
            __syncthreads();
            gll16(Ah + kk, lA0p);
            gll16(Ah + kk + rstep, lA0p + 2048);
            gll16(Ah + K + kk, lA1p);
            gll16(Ah + K + kk + rstep, lA1p + 2048);
            gll16(Bh + kk, lB0p);
            gll16(Bh + kk + rstep, lB0p + 2048);
            gll16(Bh + K + kk, lB1p);
            gll16(Bh + K + kk + rstep, lB1p + 2048);
            __syncthreads();
            bf16x8 a0[4], a1[4], b0[4], b1[4];
#pragma unroll
            for (int i = 0; i < 4; ++i) a0[i] = *(const bf16x8*)&lA0[aidx + i * 512];
#pragma unroll
            for (int j = 0; j < 4; ++j) b0[j] = *(const bf16x8*)&lB0[bidx + j * 512];
#pragma unroll
            for (int i = 0; i < 4; ++i)
#pragma unroll
                for (int j = 0; j < 4; ++j)
                    acc[i][j] = __builtin_amdgcn_mfma_f32_16x16x32_bf16(a0[i], b0[j], acc[i][j], 0, 0, 0);
#pragma unroll
            for (int i = 0; i < 4; ++i) a1[i] = *(const bf16x8*)&lA1[aidx + i * 512];
#pragma unroll
            for (int i = 0; i < 4; ++i)
#pragma unroll
                for (int j = 0; j < 4; ++j)
                    acc[i][j] = __builtin_amdgcn_mfma_f32_16x16x32_bf16(a1[i], b0[j], acc[i][j], 0, 0, 0);
#pragma unroll
            for (int j = 0; j < 4; ++j) b1[j] = *(const bf16x8*)&lB1[bidx + j * 512];
#pragma unroll
            for (int i = 0; i < 4; ++i)
#pragma unroll
                for (int j = 0; j < 4; ++j)
                    acc[i][j] = __builtin_amdgcn_mfma_f32_16x16x32_bf16(a0[i], b1[j], acc[i][j], 0, 0, 0);
        }
    }

    float bj[4];
#pragma unroll
    for (int j = 0; j < 4; ++j) bj[j] = bias[n0 + wc + j * 16 + (lane & 15)];
#pragma unroll
    for (int i = 0; i < 4; ++i) {
        int row0 = m0 + wr + i * 16 + (lane >> 4) * 4;
#pragma unroll
        for (int j = 0; j < 4; ++j) {
            int col = n0 + wc + j * 16 + (lane & 15);
#pragma unroll
            for (int r = 0; r < 4; ++r) {
                float v = acc[i][j][r] + bj[j];
                C[(size_t)(row0 + r) * 1024 + col] = v > 0.f ? v : 0.f;
            }
        }
    }
}

// ---------------- scoring + top-k ----------------

__global__ __launch_bounds__(256) void pnorm_kernel(const float* __restrict__ p, float* __restrict__ out) {
    __shared__ float red[256];
    float a = 0.f;
    for (int i = threadIdx.x; i < 1024; i += 256) { float v = p[i]; a += v * v; }
    red[threadIdx.x] = a;
    __syncthreads();
    for (int s = 128; s > 0; s >>= 1) {
        if (threadIdx.x < s) red[threadIdx.x] += red[threadIdx.x + s];
        __syncthreads();
    }
    if (threadIdx.x == 0) out[0] = sqrtf(red[0]);
}

__global__ __launch_bounds__(256) void score_kernel(const float* __restrict__ h,
                                                    const float* __restrict__ p,
                                                    const float* __restrict__ pn,
                                                    float* __restrict__ s) {
    int node = blockIdx.x;
    __shared__ float red[256];
    const float* row = h + (size_t)node * 1024;
    float a = 0.f;
    for (int i = threadIdx.x; i < 1024; i += 256) a += row[i] * p[i];
    red[threadIdx.x] = a;
    __syncthreads();
    for (int t = 128; t > 0; t >>= 1) {
        if (threadIdx.x < t) red[threadIdx.x] += red[threadIdx.x + t];
        __syncthreads();
    }
    if (threadIdx.x == 0) s[node] = tanhf(red[0] / pn[0]);
}

// one block per graph; bitonic sort 1024 (score,idx) pairs descending
__global__ __launch_bounds__(1024) void topk_kernel(const float* __restrict__ s, int n, int k,
                                                    int* __restrict__ old_idx, float* __restrict__ vals,
                                                    int* __restrict__ remap) {
    __shared__ float sv[1024];
    __shared__ int si[1024];
    int b = blockIdx.x, tid = threadIdx.x;
    sv[tid] = (tid < n) ? s[b * n + tid] : -INFINITY;
    si[tid] = tid;
    if (tid < n) remap[b * n + tid] = -1;
    __syncthreads();
    for (int kk = 2; kk <= 1024; kk <<= 1) {
        for (int j = kk >> 1; j > 0; j >>= 1) {
            int ixj = tid ^ j;
            if (ixj > tid) {
                bool up = ((tid & kk) == 0);
                float a = sv[tid], bb = sv[ixj];
                bool sw = up ? (a < bb) : (a > bb);
                if (sw) {
                    sv[tid] = bb; sv[ixj] = a;
                    int t = si[tid]; si[tid] = si[ixj]; si[ixj] = t;
                }
            }
            __syncthreads();
        }
    }
    if (tid < k) {
        int old = b * n + si[tid];
        old_idx[b * k + tid] = old;
        vals[b * k + tid] = sv[tid];
        remap[old] = b * k + tid;
    }
}

__global__ __launch_bounds__(256) void compact_kernel(const float* __restrict__ h,
                                                      const int* __restrict__ old_idx,
                                                      const float* __restrict__ vals,
                                                      float* __restrict__ xn) {
    int j = blockIdx.x;
    int o = old_idx[j];
    float v = vals[j];
    const float* src = h + (size_t)o * 1024;
    float* dst = xn + (size_t)j * 1024;
    for (int f = threadIdx.x; f < 1024; f += 256) dst[f] = src[f] * v;
}

__global__ __launch_bounds__(256) void readout_kernel(const float* __restrict__ xn, int k,
                                                      float* __restrict__ out) {
    int b = blockIdx.y;
    int f = blockIdx.x * 256 + threadIdx.x;
    const float* base = xn + ((size_t)b * k) * 1024 + f;
    float mx = -INFINITY, sm = 0.f;
    for (int i = 0; i < k; ++i) {
        float v = base[(size_t)i * 1024];
        mx = fmaxf(mx, v);
        sm += v;
    }
    out[b * 2048 + f] += mx;
    out[b * 2048 + 1024 + f] += sm / (float)k;
}

// ---------------- host-side layer driver ----------------

static void run_layer(const float* cur, int K, int M, int Mp, int n_per, int k_keep,
                      const float* Wl, const float* bias, const float* Wr, const float* p,
                      ushort_t* Abig, ushort_t* Wbig, float* bufOut, float* bufNext,
                      int* esrc, int* edst, int* emask,
                      int* counts, int* offsets, int* cursor, int* adj,
                      float* scores, int* old_idx, float* vals, int* remap, float* pnormv,
                      float* out, hipStream_t stream) {
    hipMemsetAsync(counts, 0, (size_t)M * sizeof(int), stream);
    count_kernel<<<E_ / 256, 256, 0, stream>>>(edst, emask, counts);
    scan16_kernel<<<1, 1024, 0, stream>>>(counts, offsets, cursor, M);
    fill_kernel<<<E_ / 256, 256, 0, stream>>>(esrc, edst, emask, cursor, adj);
    agg_pack_kernel<<<Mp, 256, 0, stream>>>(cur, adj, offsets, counts, Abig, K, M);
    pack_w_kernel<<<(1024 * K) / 256, 256, 0, stream>>>(Wl, Wr, Wbig, K);
    gemm_mfma<<<dim3(8, Mp / 128), 256, 0, stream>>>(Abig, Wbig, bias, bufOut, K);
    pnorm_kernel<<<1, 256, 0, stream>>>(p, pnormv);
    score_kernel<<<M, 256, 0, stream>>>(bufOut, p, pnormv, scores);
    topk_kernel<<<B_, 1024, 0, stream>>>(scores, n_per, k_keep, old_idx, vals, remap);
    edge_update_kernel<<<E_ / 256, 256, 0, stream>>>(esrc, edst, emask, remap);
    compact_kernel<<<B_ * k_keep, 256, 0, stream>>>(bufOut, old_idx, vals, bufNext);
    readout_kernel<<<dim3(4, B_), 256, 0, stream>>>(bufNext, k_keep, out);
}

extern "C" void kernel_launch(void* const* d_in, const int* in_sizes, int n_in,
                              void* d_out, int out_size, void* d_ws, size_t ws_size,
                              hipStream_t stream) {
    const float* x   = (const float*)d_in[0];
    const int*   ei  = (const int*)d_in[1];
    const float* W1l = (const float*)d_in[3];
    const float* b1  = (const float*)d_in[4];
    const float* W1r = (const float*)d_in[5];
    const float* p1  = (const float*)d_in[6];
    const float* W2l = (const float*)d_in[7];
    const float* b2  = (const float*)d_in[8];
    const float* W2r = (const float*)d_in[9];
    const float* p2  = (const float*)d_in[10];
    const float* W3l = (const float*)d_in[11];
    const float* b3  = (const float*)d_in[12];
    const float* W3r = (const float*)d_in[13];
    const float* p3  = (const float*)d_in[14];
    float* out = (float*)d_out;

    char* ws = (char*)d_ws;
    size_t off = 0;
    float* bufOut = (float*)(ws + off); off += (size_t)MP1_ * 1024 * 4;            // 64 MB
    float* bufCur = (float*)(ws + off); off += (size_t)M2_ * 1024 * 4;             // 51.3 MB
    ushort_t* Abig = (ushort_t*)(ws + off); off += (size_t)MP2_ * 4096 * 2;        // 103 MB
    ushort_t* Wbig = (ushort_t*)(ws + off); off += (size_t)1024 * 4096 * 2;        // 8 MB
    char* misc = ws + off;
    float* scores = (float*)(misc + 0 * 65536);
    int*   counts = (int*)(misc + 1 * 65536);
    int*   offsets= (int*)(misc + 2 * 65536);
    int*   cursor = (int*)(misc + 3 * 65536);
    int*   old_idx= (int*)(misc + 4 * 65536);
    float* vals   = (float*)(misc + 5 * 65536);
    int*   remap  = (int*)(misc + 6 * 65536);
    float* pnormv = (float*)(misc + 7 * 65536);
    int*   adj    = (int*)(misc + 8 * 65536);
    int*   esrc   = (int*)(misc + 8 * 65536 + 1 * 1048576);
    int*   edst   = (int*)(misc + 8 * 65536 + 2 * 1048576);
    int*   emask  = (int*)(misc + 8 * 65536 + 3 * 1048576);

    hipMemsetAsync(d_out, 0, (size_t)out_size * sizeof(float), stream);
    init_edges_kernel<<<E_ / 256, 256, 0, stream>>>(ei, esrc, edst, emask);

    // layer 1: cur = x (K=512), M=16384, pool 1024->820
    run_layer(x, FEAT_, M1_, MP1_, NP_, K1_, W1l, b1, W1r, p1,
              Abig, Wbig, bufOut, bufCur, esrc, edst, emask,
              counts, offsets, cursor, adj, scores, old_idx, vals, remap, pnormv,
              out, stream);
    // layer 2: cur = pooled (K=1024), M=13120, pool 820->656
    run_layer(bufCur, H_, M2_, MP2_, K1_, K2_, W2l, b2, W2r, p2,
              Abig, Wbig, bufOut, bufCur, esrc, edst, emask,
              counts, offsets, cursor, adj, scores, old_idx, vals, remap, pnormv,
              out, stream);
    // layer 3: cur = pooled (K=1024), M=10496, pool 656->525
    run_layer(bufCur, H_, M3_, MP3_, K2_, K3_, W3l, b3, W3r, p3,
              Abig, Wbig, bufOut, bufCur, esrc, edst, emask,
              counts, offsets, cursor, adj, scores, old_idx, vals, remap, pnormv,
              out, stream);
}

// Round 4
// 1147.927 us; speedup vs baseline: 2.6363x; 1.4925x over previous
//
#include <hip/hip_runtime.h>
#include <math.h>

// Problem constants (fixed by reference)
#define B_    16
#define NP_   1024
#define FEAT_ 512
#define H_    1024
#define E_    262144          // B*NP*DEG
#define K1_   820             // ceil(0.8*1024)
#define K2_   656             // ceil(0.8*820)
#define K3_   525             // ceil(0.8*656)
#define M1_   16384           // B*NP
#define M2_   13120           // B*K1
#define M3_   10496           // B*K2
#define MP1_  16384           // padded to x128
#define MP2_  13184
#define MP3_  10496

typedef unsigned short ushort_t;
typedef __bf16 bf16x8 __attribute__((ext_vector_type(8)));
typedef float f32x4 __attribute__((ext_vector_type(4)));

// ---- bf16 split helpers (RNE) ----
__device__ inline ushort_t f2bf(float f) {
    unsigned u = __float_as_uint(f);
    u += 0x7FFF + ((u >> 16) & 1);
    return (ushort_t)(u >> 16);
}
__device__ inline float bf2f(ushort_t h) {
    return __uint_as_float(((unsigned)h) << 16);
}
__device__ inline void split1(float v, ushort_t& hi, ushort_t& lo) {
    hi = f2bf(v);
    lo = f2bf(v - bf2f(hi));
}

__device__ inline void gll16(const void* g, void* l) {
    __builtin_amdgcn_global_load_lds((__attribute__((address_space(1))) void*)g,
                                     (__attribute__((address_space(3))) void*)l, 16, 0, 0);
}

// ---------------- edge bookkeeping ----------------

__global__ void init_edges_kernel(const int* __restrict__ ei, int* __restrict__ esrc,
                                  int* __restrict__ edst, int* __restrict__ emask) {
    int e = blockIdx.x * 256 + threadIdx.x;
    esrc[e] = ei[e];
    edst[e] = ei[E_ + e];
    emask[e] = 1;
}

__global__ void count_kernel(const int* __restrict__ edst, const int* __restrict__ emask,
                             int* __restrict__ counts) {
    int e = blockIdx.x * 256 + threadIdx.x;
    if (emask[e]) atomicAdd(&counts[edst[e]], 1);
}

// single-block scan: 1024 threads x 16 items serial + one block-scan of partials
__global__ __launch_bounds__(1024) void scan16_kernel(const int* __restrict__ counts,
                                                      int* __restrict__ offsets,
                                                      int* __restrict__ cursor, int M) {
    __shared__ int part[1024];
    int t = threadIdx.x;
    int base = t * 16;
    int v[16];
    int s = 0;
#pragma unroll
    for (int i = 0; i < 16; ++i) {
        int idx = base + i;
        v[i] = s;
        int c = (idx < M) ? counts[idx] : 0;
        s += c;
    }
    part[t] = s;
    __syncthreads();
    for (int off = 1; off < 1024; off <<= 1) {
        int tv = (t >= off) ? part[t - off] : 0;
        __syncthreads();
        part[t] += tv;
        __syncthreads();
    }
    int excl = part[t] - s;
#pragma unroll
    for (int i = 0; i < 16; ++i) {
        int idx = base + i;
        if (idx < M) {
            int o = excl + v[i];
            offsets[idx] = o;
            cursor[idx] = o;
        }
    }
}

__global__ void fill_kernel(const int* __restrict__ esrc, const int* __restrict__ edst,
                            const int* __restrict__ emask, int* __restrict__ cursor,
                            int* __restrict__ adj) {
    int e = blockIdx.x * 256 + threadIdx.x;
    if (emask[e]) {
        int pos = atomicAdd(&cursor[edst[e]], 1);
        adj[pos] = esrc[e];
    }
}

__global__ void edge_update_kernel(int* __restrict__ esrc, int* __restrict__ edst,
                                   int* __restrict__ emask, const int* __restrict__ remap) {
    int e = blockIdx.x * 256 + threadIdx.x;
    if (emask[e]) {
        int ns = remap[esrc[e]];
        int nd = remap[edst[e]];
        if (ns >= 0 && nd >= 0) { esrc[e] = ns; edst[e] = nd; }
        else { esrc[e] = 0; edst[e] = 0; emask[e] = 0; }
    } else {
        esrc[e] = 0; edst[e] = 0;
    }
}

// ---------------- fused aggregation + pack, float4 gather, XCD-swizzled ----------------
// Abig row layout (4K cols, bf16): [agg_hi(K) | agg_lo(K) | cur_hi(K) | cur_lo(K)]
// Block b runs on XCD b%8 (dispatch round-robin heuristic); graphs {x, x+8} -> XCD x
// so the per-XCD gather working set (2 graphs of features) is L2-resident.

// K=1024: 1 node/block, 256 threads = 256 float4 cols. blocks = 16*n_per.
__global__ __launch_bounds__(256) void agg_pack_k1024(const float* __restrict__ x,
                                                      const int* __restrict__ adj,
                                                      const int* __restrict__ offsets,
                                                      const int* __restrict__ counts,
                                                      ushort_t* __restrict__ Abig,
                                                      int n_per) {
    int b = blockIdx.x;
    int q = b >> 3;
    int over = (q >= n_per) ? 1 : 0;
    int g = (b & 7) + over * 8;
    int node = g * n_per + (q - over * n_per);
    int start = offsets[node], cnt = counts[node];
    float d = fmaxf((float)cnt, 1.0f);
    int c = threadIdx.x;
    const float4* xb = (const float4*)x + c;
    float ax = 0.f, ay = 0.f, az = 0.f, aw = 0.f;
    int j = 0;
    for (; j + 4 <= cnt; j += 4) {
        int s0 = adj[start + j + 0];
        int s1 = adj[start + j + 1];
        int s2 = adj[start + j + 2];
        int s3 = adj[start + j + 3];
        float4 v0 = xb[(size_t)s0 * 256];
        float4 v1 = xb[(size_t)s1 * 256];
        float4 v2 = xb[(size_t)s2 * 256];
        float4 v3 = xb[(size_t)s3 * 256];
        ax += (v0.x + v1.x) + (v2.x + v3.x);
        ay += (v0.y + v1.y) + (v2.y + v3.y);
        az += (v0.z + v1.z) + (v2.z + v3.z);
        aw += (v0.w + v1.w) + (v2.w + v3.w);
    }
    for (; j < cnt; ++j) {
        float4 v = xb[(size_t)adj[start + j] * 256];
        ax += v.x; ay += v.y; az += v.z; aw += v.w;
    }
    float inv = 1.0f / d;
    float4 cv = xb[(size_t)node * 256];
    ushort_t* row = Abig + (size_t)node * 4096;
    ushort4 mh, ml, ch, cl;
    split1(ax * inv, mh.x, ml.x); split1(ay * inv, mh.y, ml.y);
    split1(az * inv, mh.z, ml.z); split1(aw * inv, mh.w, ml.w);
    split1(cv.x, ch.x, cl.x); split1(cv.y, ch.y, cl.y);
    split1(cv.z, ch.z, cl.z); split1(cv.w, ch.w, cl.w);
    *(ushort4*)&row[c * 4]        = mh;
    *(ushort4*)&row[1024 + c * 4] = ml;
    *(ushort4*)&row[2048 + c * 4] = ch;
    *(ushort4*)&row[3072 + c * 4] = cl;
}

// K=512: 2 nodes/block (threads 0-127 node0, 128-255 node0+1). blocks = 8192.
__global__ __launch_bounds__(256) void agg_pack_k512(const float* __restrict__ x,
                                                     const int* __restrict__ adj,
                                                     const int* __restrict__ offsets,
                                                     const int* __restrict__ counts,
                                                     ushort_t* __restrict__ Abig) {
    int b = blockIdx.x;
    int q = b >> 3;                       // [0, 1024) pair index
    int over = (q >= 512) ? 1 : 0;
    int g = (b & 7) + over * 8;
    int node = g * 1024 + (q - over * 512) * 2 + (threadIdx.x >> 7);
    int start = offsets[node], cnt = counts[node];
    float d = fmaxf((float)cnt, 1.0f);
    int c = threadIdx.x & 127;
    const float4* xb = (const float4*)x + c;
    float ax = 0.f, ay = 0.f, az = 0.f, aw = 0.f;
    int j = 0;
    for (; j + 4 <= cnt; j += 4) {
        int s0 = adj[start + j + 0];
        int s1 = adj[start + j + 1];
        int s2 = adj[start + j + 2];
        int s3 = adj[start + j + 3];
        float4 v0 = xb[(size_t)s0 * 128];
        float4 v1 = xb[(size_t)s1 * 128];
        float4 v2 = xb[(size_t)s2 * 128];
        float4 v3 = xb[(size_t)s3 * 128];
        ax += (v0.x + v1.x) + (v2.x + v3.x);
        ay += (v0.y + v1.y) + (v2.y + v3.y);
        az += (v0.z + v1.z) + (v2.z + v3.z);
        aw += (v0.w + v1.w) + (v2.w + v3.w);
    }
    for (; j < cnt; ++j) {
        float4 v = xb[(size_t)adj[start + j] * 128];
        ax += v.x; ay += v.y; az += v.z; aw += v.w;
    }
    float inv = 1.0f / d;
    float4 cv = xb[(size_t)node * 128];
    ushort_t* row = Abig + (size_t)node * 2048;
    ushort4 mh, ml, ch, cl;
    split1(ax * inv, mh.x, ml.x); split1(ay * inv, mh.y, ml.y);
    split1(az * inv, mh.z, ml.z); split1(aw * inv, mh.w, ml.w);
    split1(cv.x, ch.x, cl.x); split1(cv.y, ch.y, cl.y);
    split1(cv.z, ch.z, cl.z); split1(cv.w, ch.w, cl.w);
    *(ushort4*)&row[c * 4]        = mh;
    *(ushort4*)&row[512 + c * 4]  = ml;
    *(ushort4*)&row[1024 + c * 4] = ch;
    *(ushort4*)&row[1536 + c * 4] = cl;
}

__global__ __launch_bounds__(256) void pack_w_kernel(const float* __restrict__ Wl,
                                                     const float* __restrict__ Wr,
                                                     ushort_t* __restrict__ Wbig, int K) {
    int idx = blockIdx.x * 256 + threadIdx.x;    // over 1024*K
    int n = idx / K;
    int k = idx - n * K;
    ushort_t* row = Wbig + (size_t)n * (4 * K);
    float a = Wl[idx];
    ushort_t ah = f2bf(a);
    row[k] = ah;
    row[K + k] = f2bf(a - bf2f(ah));
    float b = Wr[idx];
    ushort_t bh = f2bf(b);
    row[2 * K + k] = bh;
    row[3 * K + k] = f2bf(b - bf2f(bh));
}

// ---------------- MFMA GEMM, two super-segments, XOR-swizzled LDS ----------------
// grid = (Mp/128, 8): row-panel index in x so the 8 col-blocks of one A panel
// land on one XCD (dispatch x%8) -> A read once per XCD-L2; W (8 MB) replicates.

__global__ __launch_bounds__(256) void gemm_mfma(const ushort_t* __restrict__ Ab,
                                                 const ushort_t* __restrict__ Wb,
                                                 const float* __restrict__ bias,
                                                 float* __restrict__ C, int K) {
    __shared__ ushort_t lA0[4096];
    __shared__ ushort_t lA1[4096];
    __shared__ ushort_t lB0[4096];
    __shared__ ushort_t lB1[4096];
    const int LD = 4 * K;
    int tid = threadIdx.x;
    int lane = tid & 63;
    int w = tid >> 6;
    int wr = (w >> 1) * 64, wc = (w & 1) * 64;
    int m0 = blockIdx.x * 128, n0 = blockIdx.y * 128;

    int srow = tid >> 2;
    int gq = (tid & 3) ^ ((tid >> 2) & 3) ^ ((tid >> 4) & 3);
    const ushort_t* Ag = Ab + (size_t)(m0 + srow) * LD + gq * 8;
    const ushort_t* Bg = Wb + (size_t)(n0 + srow) * LD + gq * 8;
    ushort_t* lA0p = &lA0[tid * 8];
    ushort_t* lA1p = &lA1[tid * 8];
    ushort_t* lB0p = &lB0[tid * 8];
    ushort_t* lB1p = &lB1[tid * 8];
    const size_t rstep = (size_t)64 * LD;

    int qsw = (lane >> 4) ^ (lane & 3) ^ ((lane >> 2) & 3);
    int aidx = (wr + (lane & 15)) * 32 + qsw * 8;
    int bidx = (wc + (lane & 15)) * 32 + qsw * 8;

    f32x4 acc[4][4];
#pragma unroll
    for (int i = 0; i < 4; ++i)
#pragma unroll
        for (int j = 0; j < 4; ++j) acc[i][j] = (f32x4){0.f, 0.f, 0.f, 0.f};

    for (int ss = 0; ss < 2; ++ss) {
        const ushort_t* Ah = Ag + ss * 2 * K;
        const ushort_t* Bh = Bg + ss * 2 * K;
        for (int kk = 0; kk < K; kk += 32) {
            __syncthreads();
            gll16(Ah + kk, lA0p);
            gll16(Ah + kk + rstep, lA0p + 2048);
            gll16(Ah + K + kk, lA1p);
            gll16(Ah + K + kk + rstep, lA1p + 2048);
            gll16(Bh + kk, lB0p);
            gll16(Bh + kk + rstep, lB0p + 2048);
            gll16(Bh + K + kk, lB1p);
            gll16(Bh + K + kk + rstep, lB1p + 2048);
            __syncthreads();
            bf16x8 a0[4], a1[4], b0[4], b1[4];
#pragma unroll
            for (int i = 0; i < 4; ++i) a0[i] = *(const bf16x8*)&lA0[aidx + i * 512];
#pragma unroll
            for (int j = 0; j < 4; ++j) b0[j] = *(const bf16x8*)&lB0[bidx + j * 512];
#pragma unroll
            for (int i = 0; i < 4; ++i)
#pragma unroll
                for (int j = 0; j < 4; ++j)
                    acc[i][j] = __builtin_amdgcn_mfma_f32_16x16x32_bf16(a0[i], b0[j], acc[i][j], 0, 0, 0);
#pragma unroll
            for (int i = 0; i < 4; ++i) a1[i] = *(const bf16x8*)&lA1[aidx + i * 512];
#pragma unroll
            for (int i = 0; i < 4; ++i)
#pragma unroll
                for (int j = 0; j < 4; ++j)
                    acc[i][j] = __builtin_amdgcn_mfma_f32_16x16x32_bf16(a1[i], b0[j], acc[i][j], 0, 0, 0);
#pragma unroll
            for (int j = 0; j < 4; ++j) b1[j] = *(const bf16x8*)&lB1[bidx + j * 512];
#pragma unroll
            for (int i = 0; i < 4; ++i)
#pragma unroll
                for (int j = 0; j < 4; ++j)
                    acc[i][j] = __builtin_amdgcn_mfma_f32_16x16x32_bf16(a0[i], b1[j], acc[i][j], 0, 0, 0);
        }
    }

    float bj[4];
#pragma unroll
    for (int j = 0; j < 4; ++j) bj[j] = bias[n0 + wc + j * 16 + (lane & 15)];
#pragma unroll
    for (int i = 0; i < 4; ++i) {
        int row0 = m0 + wr + i * 16 + (lane >> 4) * 4;
#pragma unroll
        for (int j = 0; j < 4; ++j) {
            int col = n0 + wc + j * 16 + (lane & 15);
#pragma unroll
            for (int r = 0; r < 4; ++r) {
                float v = acc[i][j][r] + bj[j];
                C[(size_t)(row0 + r) * 1024 + col] = v > 0.f ? v : 0.f;
            }
        }
    }
}

// ---------------- scoring + top-k ----------------

__global__ __launch_bounds__(256) void pnorm_kernel(const float* __restrict__ p, float* __restrict__ out) {
    __shared__ float red[256];
    float a = 0.f;
    for (int i = threadIdx.x; i < 1024; i += 256) { float v = p[i]; a += v * v; }
    red[threadIdx.x] = a;
    __syncthreads();
    for (int s = 128; s > 0; s >>= 1) {
        if (threadIdx.x < s) red[threadIdx.x] += red[threadIdx.x + s];
        __syncthreads();
    }
    if (threadIdx.x == 0) out[0] = sqrtf(red[0]);
}

__global__ __launch_bounds__(256) void score_kernel(const float* __restrict__ h,
                                                    const float* __restrict__ p,
                                                    const float* __restrict__ pn,
                                                    float* __restrict__ s) {
    int node = blockIdx.x;
    __shared__ float red[256];
    const float4* row = (const float4*)(h + (size_t)node * 1024);
    const float4* pv = (const float4*)p;
    float4 a4 = row[threadIdx.x];
    float4 p4 = pv[threadIdx.x];
    float a = a4.x * p4.x + a4.y * p4.y + a4.z * p4.z + a4.w * p4.w;
    red[threadIdx.x] = a;
    __syncthreads();
    for (int t = 128; t > 0; t >>= 1) {
        if (threadIdx.x < t) red[threadIdx.x] += red[threadIdx.x + t];
        __syncthreads();
    }
    if (threadIdx.x == 0) s[node] = tanhf(red[0] / pn[0]);
}

// one block per graph; bitonic sort 1024 (score,idx) pairs descending
__global__ __launch_bounds__(1024) void topk_kernel(const float* __restrict__ s, int n, int k,
                                                    int* __restrict__ old_idx, float* __restrict__ vals,
                                                    int* __restrict__ remap) {
    __shared__ float sv[1024];
    __shared__ int si[1024];
    int b = blockIdx.x, tid = threadIdx.x;
    sv[tid] = (tid < n) ? s[b * n + tid] : -INFINITY;
    si[tid] = tid;
    if (tid < n) remap[b * n + tid] = -1;
    __syncthreads();
    for (int kk = 2; kk <= 1024; kk <<= 1) {
        for (int j = kk >> 1; j > 0; j >>= 1) {
            int ixj = tid ^ j;
            if (ixj > tid) {
                bool up = ((tid & kk) == 0);
                float a = sv[tid], bb = sv[ixj];
                bool sw = up ? (a < bb) : (a > bb);
                if (sw) {
                    sv[tid] = bb; sv[ixj] = a;
                    int t = si[tid]; si[tid] = si[ixj]; si[ixj] = t;
                }
            }
            __syncthreads();
        }
    }
    if (tid < k) {
        int old = b * n + si[tid];
        old_idx[b * k + tid] = old;
        vals[b * k + tid] = sv[tid];
        remap[old] = b * k + tid;
    }
}

__global__ __launch_bounds__(256) void compact_kernel(const float* __restrict__ h,
                                                      const int* __restrict__ old_idx,
                                                      const float* __restrict__ vals,
                                                      float* __restrict__ xn) {
    int j = blockIdx.x;
    int o = old_idx[j];
    float v = vals[j];
    const float4* src = (const float4*)(h + (size_t)o * 1024);
    float4* dst = (float4*)(xn + (size_t)j * 1024);
    float4 t = src[threadIdx.x];
    t.x *= v; t.y *= v; t.z *= v; t.w *= v;
    dst[threadIdx.x] = t;
}

__global__ __launch_bounds__(256) void readout_kernel(const float* __restrict__ xn, int k,
                                                      float* __restrict__ out) {
    int b = blockIdx.x;
    int c = threadIdx.x;                  // float4 col, 256 x 4 = 1024
    const float4* base = (const float4*)xn + (size_t)b * k * 256 + c;
    float4 mx = {-INFINITY, -INFINITY, -INFINITY, -INFINITY};
    float4 sm = {0.f, 0.f, 0.f, 0.f};
    int i = 0;
    for (; i + 4 <= k; i += 4) {
        float4 v0 = base[(size_t)(i + 0) * 256];
        float4 v1 = base[(size_t)(i + 1) * 256];
        float4 v2 = base[(size_t)(i + 2) * 256];
        float4 v3 = base[(size_t)(i + 3) * 256];
        mx.x = fmaxf(fmaxf(fmaxf(mx.x, v0.x), fmaxf(v1.x, v2.x)), v3.x);
        mx.y = fmaxf(fmaxf(fmaxf(mx.y, v0.y), fmaxf(v1.y, v2.y)), v3.y);
        mx.z = fmaxf(fmaxf(fmaxf(mx.z, v0.z), fmaxf(v1.z, v2.z)), v3.z);
        mx.w = fmaxf(fmaxf(fmaxf(mx.w, v0.w), fmaxf(v1.w, v2.w)), v3.w);
        sm.x += (v0.x + v1.x) + (v2.x + v3.x);
        sm.y += (v0.y + v1.y) + (v2.y + v3.y);
        sm.z += (v0.z + v1.z) + (v2.z + v3.z);
        sm.w += (v0.w + v1.w) + (v2.w + v3.w);
    }
    for (; i < k; ++i) {
        float4 v = base[(size_t)i * 256];
        mx.x = fmaxf(mx.x, v.x); mx.y = fmaxf(mx.y, v.y);
        mx.z = fmaxf(mx.z, v.z); mx.w = fmaxf(mx.w, v.w);
        sm.x += v.x; sm.y += v.y; sm.z += v.z; sm.w += v.w;
    }
    float invk = 1.0f / (float)k;
    float* o0 = out + (size_t)b * 2048 + c * 4;
    o0[0] += mx.x; o0[1] += mx.y; o0[2] += mx.z; o0[3] += mx.w;
    float* o1 = o0 + 1024;
    o1[0] += sm.x * invk; o1[1] += sm.y * invk; o1[2] += sm.z * invk; o1[3] += sm.w * invk;
}

// ---------------- host-side layer driver ----------------

static void run_layer(const float* cur, int K, int M, int Mp, int n_per, int k_keep,
                      const float* Wl, const float* bias, const float* Wr, const float* p,
                      ushort_t* Abig, ushort_t* Wbig, float* bufOut, float* bufNext,
                      int* esrc, int* edst, int* emask,
                      int* counts, int* offsets, int* cursor, int* adj,
                      float* scores, int* old_idx, float* vals, int* remap, float* pnormv,
                      float* out, hipStream_t stream) {
    hipMemsetAsync(counts, 0, (size_t)M * sizeof(int), stream);
    count_kernel<<<E_ / 256, 256, 0, stream>>>(edst, emask, counts);
    scan16_kernel<<<1, 1024, 0, stream>>>(counts, offsets, cursor, M);
    fill_kernel<<<E_ / 256, 256, 0, stream>>>(esrc, edst, emask, cursor, adj);
    if (Mp > M)   // zero pad rows of Abig (layer 2)
        hipMemsetAsync(Abig + (size_t)M * 4 * K, 0, (size_t)(Mp - M) * 4 * K * 2, stream);
    if (K == 512)
        agg_pack_k512<<<8192, 256, 0, stream>>>(cur, adj, offsets, counts, Abig);
    else
        agg_pack_k1024<<<M, 256, 0, stream>>>(cur, adj, offsets, counts, Abig, n_per);
    pack_w_kernel<<<(1024 * K) / 256, 256, 0, stream>>>(Wl, Wr, Wbig, K);
    gemm_mfma<<<dim3(Mp / 128, 8), 256, 0, stream>>>(Abig, Wbig, bias, bufOut, K);
    pnorm_kernel<<<1, 256, 0, stream>>>(p, pnormv);
    score_kernel<<<M, 256, 0, stream>>>(bufOut, p, pnormv, scores);
    topk_kernel<<<B_, 1024, 0, stream>>>(scores, n_per, k_keep, old_idx, vals, remap);
    edge_update_kernel<<<E_ / 256, 256, 0, stream>>>(esrc, edst, emask, remap);
    compact_kernel<<<B_ * k_keep, 256, 0, stream>>>(bufOut, old_idx, vals, bufNext);
    readout_kernel<<<B_, 256, 0, stream>>>(bufNext, k_keep, out);
}

extern "C" void kernel_launch(void* const* d_in, const int* in_sizes, int n_in,
                              void* d_out, int out_size, void* d_ws, size_t ws_size,
                              hipStream_t stream) {
    const float* x   = (const float*)d_in[0];
    const int*   ei  = (const int*)d_in[1];
    const float* W1l = (const float*)d_in[3];
    const float* b1  = (const float*)d_in[4];
    const float* W1r = (const float*)d_in[5];
    const float* p1  = (const float*)d_in[6];
    const float* W2l = (const float*)d_in[7];
    const float* b2  = (const float*)d_in[8];
    const float* W2r = (const float*)d_in[9];
    const float* p2  = (const float*)d_in[10];
    const float* W3l = (const float*)d_in[11];
    const float* b3  = (const float*)d_in[12];
    const float* W3r = (const float*)d_in[13];
    const float* p3  = (const float*)d_in[14];
    float* out = (float*)d_out;

    char* ws = (char*)d_ws;
    size_t off = 0;
    float* bufOut = (float*)(ws + off); off += (size_t)MP1_ * 1024 * 4;            // 64 MB
    float* bufCur = (float*)(ws + off); off += (size_t)M2_ * 1024 * 4;             // 51.3 MB
    ushort_t* Abig = (ushort_t*)(ws + off); off += (size_t)MP2_ * 4096 * 2;        // 103 MB
    ushort_t* Wbig = (ushort_t*)(ws + off); off += (size_t)1024 * 4096 * 2;        // 8 MB
    char* misc = ws + off;
    float* scores = (float*)(misc + 0 * 65536);
    int*   counts = (int*)(misc + 1 * 65536);
    int*   offsets= (int*)(misc + 2 * 65536);
    int*   cursor = (int*)(misc + 3 * 65536);
    int*   old_idx= (int*)(misc + 4 * 65536);
    float* vals   = (float*)(misc + 5 * 65536);
    int*   remap  = (int*)(misc + 6 * 65536);
    float* pnormv = (float*)(misc + 7 * 65536);
    int*   adj    = (int*)(misc + 8 * 65536);
    int*   esrc   = (int*)(misc + 8 * 65536 + 1 * 1048576);
    int*   edst   = (int*)(misc + 8 * 65536 + 2 * 1048576);
    int*   emask  = (int*)(misc + 8 * 65536 + 3 * 1048576);

    hipMemsetAsync(d_out, 0, (size_t)out_size * sizeof(float), stream);
    init_edges_kernel<<<E_ / 256, 256, 0, stream>>>(ei, esrc, edst, emask);

    // layer 1: cur = x (K=512), M=16384, pool 1024->820
    run_layer(x, FEAT_, M1_, MP1_, NP_, K1_, W1l, b1, W1r, p1,
              Abig, Wbig, bufOut, bufCur, esrc, edst, emask,
              counts, offsets, cursor, adj, scores, old_idx, vals, remap, pnormv,
              out, stream);
    // layer 2: cur = pooled (K=1024), M=13120, pool 820->656
    run_layer(bufCur, H_, M2_, MP2_, K1_, K2_, W2l, b2, W2r, p2,
              Abig, Wbig, bufOut, bufCur, esrc, edst, emask,
              counts, offsets, cursor, adj, scores, old_idx, vals, remap, pnormv,
              out, stream);
    // layer 3: cur = pooled (K=1024), M=10496, pool 656->525
    run_layer(bufCur, H_, M3_, MP3_, K2_, K3_, W3l, b3, W3r, p3,
              Abig, Wbig, bufOut, bufCur, esrc, edst, emask,
              counts, offsets, cursor, adj, scores, old_idx, vals, remap, pnormv,
              out, stream);
}